// Round 10
// baseline (358.079 us; speedup 1.0000x reference)
//
#include <hip/hip_runtime.h>
#include <math.h>

// HistogramBinningCalibrationByFeature
// d_out: [0..N) calibrated_prediction (f32) | [N..2N) bin ids (f32-encoded)
//
// R9/R10 (resubmit after infra timeout): cross-tile software pipeline. Each
// block grid-strides over 8192-elem tiles; the NEXT tile's 6 stream loads are
// issued BEFORE the current tile's gather/LDS/VALU/store phase, so HBM
// latency+BW hides under compute and the per-CU pipes stop convoying (R8
// showed additive phase costs: 3.2 cyc/elem vs 1.9 overlapped floor). 3-bit
// LDS ratio table (80.6 KB, 2 blocks/CU) unchanged from R8. shfl/lane63
// replaced by a uniform seg_len[e+4] load.

constexpr int kNumBins     = 5000;
constexpr int kNumSegments = 42;
constexpr int kNumInterval = (kNumSegments + 1) * kNumBins;   // 215000
constexpr int kGroups      = (kNumInterval + 31) / 32;        // 6719
constexpr int kTabWords    = kGroups * 3;                     // 20157
constexpr int kGuardWord   = kTabWords;                       // read guard
constexpr int kLpwWord     = kTabWords + 1;
constexpr int kStageWords  = kTabWords + 1;                   // table + guard
constexpr float kDecode    = 0.9995f / 6.0f;
constexpr float kEncode    = 6.0f / 0.9995f;

typedef float f32x4 __attribute__((ext_vector_type(4)));
typedef int   i32x4 __attribute__((ext_vector_type(4)));

__device__ __forceinline__ unsigned int funnel_r(unsigned int hi, unsigned int lo, int sh) {
#if __has_builtin(__builtin_amdgcn_alignbit)
    return __builtin_amdgcn_alignbit(hi, lo, (unsigned int)sh);
#else
    unsigned long long v = ((unsigned long long)hi << 32) | lo;
    return (unsigned int)(v >> sh);
#endif
}

// One thread per 32-code group: 32 codes * 3 bits = 3 words, no straddle
// across group boundaries.
__global__ __launch_bounds__(256) void pack_kernel(
    const float* __restrict__ bin_pos,
    const float* __restrict__ bin_num,
    const float* __restrict__ pos_w,
    unsigned int* __restrict__ packed)   // [kTabWords + 2] in d_ws
{
    const int g = blockIdx.x * 256 + threadIdx.x;
    if (g < kGroups) {
        unsigned int w[3] = {0, 0, 0};
        int bitpos = 0;
        #pragma unroll
        for (int j = 0; j < 32; ++j) {
            const int i = g * 32 + j;
            unsigned int code = 7u;                  // invalid sentinel / pad
            if (i < kNumInterval) {
                const float nm = bin_num[i];
                if (nm > 0.0f) {
                    const float r = (bin_pos[i] / nm) * 0.9995f;  // [0, 0.9995]
                    int c = (int)(r * kEncode + 0.5f);
                    c = c < 0 ? 0 : (c > 6 ? 6 : c);
                    code = (unsigned int)c;
                }
            }
            const int word = bitpos >> 5;
            const int sh   = bitpos & 31;
            w[word] |= code << sh;
            if (sh > 29 && word < 2)                 // straddles into next word
                w[word + 1] |= code >> (32 - sh);
            bitpos += 3;
        }
        packed[g * 3 + 0] = w[0];
        packed[g * 3 + 1] = w[1];
        packed[g * 3 + 2] = w[2];
    }
    if (g == 0) {
        packed[kGuardWord] = 0u;
        packed[kLpwWord]   = __float_as_uint((float)log((double)pos_w[0]));
    }
}

__device__ __forceinline__ void process4_lds(
    const float* __restrict__ l, const int* __restrict__ s,
    const int* __restrict__ seg_val, const unsigned int* __restrict__ tab,
    float lpw, float* __restrict__ op, float* __restrict__ ob)
{
    constexpr float kInvStep = 1.0f / 0.0002f;

    int ds[4];
    #pragma unroll
    for (int j = 0; j < 4; ++j) {
        int d = 0;
        if (s[j + 1] > s[j]) {                     // predicated gather
            const int sv = seg_val[s[j]] + 1;
            d = (sv > kNumSegments) ? 0 : sv;
        }
        ds[j] = d;
    }

    float p[4]; int bin[4];
    #pragma unroll
    for (int j = 0; j < 4; ++j) {
        const float x  = l[j] + lpw;
        const float e  = __expf(-x);               // v_exp_f32 path
        const float pf = __builtin_amdgcn_rcpf(1.0f + e);
        p[j]   = pf;
        bin[j] = (int)(__builtin_ceilf(pf * kInvStep) - 1.0f) + ds[j] * kNumBins;
    }

    unsigned int lo[4], hi[4]; int sh[4];
    #pragma unroll
    for (int j = 0; j < 4; ++j) {
        int idx = bin[j];
        idx = idx < 0 ? 0 : idx;
        idx = idx > (kNumInterval - 1) ? (kNumInterval - 1) : idx;
        const int bitoff = idx * 3;
        const int w = bitoff >> 5;
        sh[j] = bitoff & 31;
        lo[j] = tab[w];                            // random LDS reads
        hi[j] = tab[w + 1];
    }

    #pragma unroll
    for (int j = 0; j < 4; ++j) {
        const unsigned int code = funnel_r(hi[j], lo[j], sh[j]) & 7u;
        const float r = (float)code * kDecode;
        op[j] = (code == 7u) ? p[j] : fmaf(p[j], 0.0005f, r);
        ob[j] = (float)bin[j];
    }
}

__global__ __launch_bounds__(1024, 8) void hbc_pipe(
    const int*          __restrict__ seg_val,   // [N]
    const int*          __restrict__ seg_len,   // [N+1]
    const float*        __restrict__ logit,     // [N]
    const unsigned int* __restrict__ packed,    // [kTabWords+2] (ws)
    float*              __restrict__ out_pred,  // [N]
    float*              __restrict__ out_bin,   // [N]
    int n)
{
    __shared__ unsigned int tab[20160];          // 80640 B -> 2 blocks/CU

    const int tid = threadIdx.x;

    for (int w = tid; w < kStageWords; w += 1024)   // stage table + guard
        tab[w] = packed[w];
    const float lpw = __uint_as_float(packed[kLpwWord]);
    __syncthreads();

    const long ntiles = (long)n >> 13;           // full 8192-elem tiles
    const long stride = gridDim.x;
    long tile = blockIdx.x;

    if (tile < ntiles) {
        // ---- prologue: issue first tile's stream loads ----
        long e0 = (tile << 13) + (long)tid * 4;
        long e1 = e0 + 4096;
        f32x4 L0 = __builtin_nontemporal_load((const f32x4*)(logit   + e0));
        f32x4 L1 = __builtin_nontemporal_load((const f32x4*)(logit   + e1));
        i32x4 S0 = __builtin_nontemporal_load((const i32x4*)(seg_len + e0));
        i32x4 S1 = __builtin_nontemporal_load((const i32x4*)(seg_len + e1));
        int  sE0 = seg_len[e0 + 4];              // uniform overlap load
        int  sE1 = seg_len[e1 + 4];

        for (;;) {
            const long next = tile + stride;
            const bool more = next < ntiles;

            // ---- issue NEXT tile's loads before consuming current ----
            f32x4 nL0, nL1; i32x4 nS0, nS1; int nsE0 = 0, nsE1 = 0;
            if (more) {
                const long f0 = (next << 13) + (long)tid * 4;
                const long f1 = f0 + 4096;
                nL0 = __builtin_nontemporal_load((const f32x4*)(logit   + f0));
                nL1 = __builtin_nontemporal_load((const f32x4*)(logit   + f1));
                nS0 = __builtin_nontemporal_load((const i32x4*)(seg_len + f0));
                nS1 = __builtin_nontemporal_load((const i32x4*)(seg_len + f1));
                nsE0 = seg_len[f0 + 4];
                nsE1 = seg_len[f1 + 4];
            }

            // ---- process current tile (loads already landed / landing) ----
            {
                const float l0[4] = {L0[0], L0[1], L0[2], L0[3]};
                const float l1[4] = {L1[0], L1[1], L1[2], L1[3]};
                const int   s0[5] = {S0[0], S0[1], S0[2], S0[3], sE0};
                const int   s1[5] = {S1[0], S1[1], S1[2], S1[3], sE1};

                f32x4 op0, ob0, op1, ob1;
                process4_lds(l0, s0, seg_val, tab, lpw, (float*)&op0, (float*)&ob0);
                process4_lds(l1, s1, seg_val, tab, lpw, (float*)&op1, (float*)&ob1);

                __builtin_nontemporal_store(op0, (f32x4*)(out_pred + e0));
                __builtin_nontemporal_store(op1, (f32x4*)(out_pred + e1));
                __builtin_nontemporal_store(ob0, (f32x4*)(out_bin  + e0));
                __builtin_nontemporal_store(ob1, (f32x4*)(out_bin  + e1));
            }

            if (!more) break;
            tile = next;
            e0 = (tile << 13) + (long)tid * 4;
            e1 = e0 + 4096;
            L0 = nL0; L1 = nL1; S0 = nS0; S1 = nS1; sE0 = nsE0; sE1 = nsE1;
        }
    }

    // tail (N % 8192), scalar + bounds-checked
    constexpr float kInvStep = 1.0f / 0.0002f;
    const long tailStart = ntiles << 13;
    for (long i = tailStart + (long)blockIdx.x * 1024 + tid; i < (long)n;
         i += (long)gridDim.x * 1024) {
        const float x  = logit[i] + lpw;
        const float pf = __builtin_amdgcn_rcpf(1.0f + __expf(-x));
        int d = 0;
        if (seg_len[i + 1] > seg_len[i]) {
            const int sv = seg_val[seg_len[i]] + 1;
            d = (sv > kNumSegments) ? 0 : sv;
        }
        const int bin = (int)(__builtin_ceilf(pf * kInvStep) - 1.0f) + d * kNumBins;
        int idx = bin < 0 ? 0 : (bin > kNumInterval - 1 ? kNumInterval - 1 : bin);
        const int bitoff = idx * 3;
        const unsigned int code =
            funnel_r(tab[(bitoff >> 5) + 1], tab[bitoff >> 5], bitoff & 31) & 7u;
        const float r = (float)code * kDecode;
        out_pred[i] = (code == 7u) ? pf : fmaf(pf, 0.0005f, r);
        out_bin[i]  = (float)bin;
    }
}

// Fallback if ws is too small: direct two-table global-gather version.
__global__ __launch_bounds__(256) void hbc_direct(
    const int*   __restrict__ seg_val,
    const int*   __restrict__ seg_len,
    const float* __restrict__ logit,
    const float* __restrict__ bin_pos,
    const float* __restrict__ bin_num,
    const float* __restrict__ pos_w,
    float*       __restrict__ out_pred,
    float*       __restrict__ out_bin,
    int n)
{
    const float kStep = 0.0002f;
    const float lpw = logf(pos_w[0]);
    for (long i = (long)blockIdx.x * blockDim.x + threadIdx.x; i < (long)n;
         i += (long)gridDim.x * blockDim.x) {
        const float x  = logit[i] + lpw;
        const float pf = 1.0f / (1.0f + expf(-x));
        int d = 0;
        if (seg_len[i + 1] > seg_len[i]) {
            const int sv = seg_val[seg_len[i]] + 1;
            d = (sv > kNumSegments) ? 0 : sv;
        }
        const int bin = (int)(ceilf(pf / kStep) - 1.0f) + d * kNumBins;
        int idx = bin < 0 ? 0 : (bin > kNumInterval - 1 ? kNumInterval - 1 : bin);
        const float cp = bin_pos[idx];
        const float cn = bin_num[idx];
        const float ctr = (cp / cn) * 0.9995f + pf * 0.0005f;
        out_pred[i] = (cn > 0.0f) ? ctr : pf;
        out_bin[i]  = (float)bin;
    }
}

extern "C" void kernel_launch(void* const* d_in, const int* in_sizes, int n_in,
                              void* d_out, int out_size, void* d_ws, size_t ws_size,
                              hipStream_t stream) {
    const int*   seg_val = (const int*)  d_in[0];
    const int*   seg_len = (const int*)  d_in[1];
    const float* logit   = (const float*)d_in[2];
    const float* bin_pos = (const float*)d_in[3];
    const float* bin_num = (const float*)d_in[4];
    const float* pos_w   = (const float*)d_in[5];

    const int n = in_sizes[2];
    float* out_pred = (float*)d_out;
    float* out_bin  = (float*)d_out + n;

    const size_t ws_needed = (size_t)(kTabWords + 2) * sizeof(unsigned int);

    if (ws_size >= ws_needed) {
        unsigned int* packed = (unsigned int*)d_ws;
        const int blocks_prep = (kGroups + 255) / 256;
        pack_kernel<<<blocks_prep, 256, 0, stream>>>(bin_pos, bin_num, pos_w, packed);
        // 512 blocks = exactly 2 resident/CU; each runs ~5 pipelined tiles.
        hbc_pipe<<<512, 1024, 0, stream>>>(
            seg_val, seg_len, logit, packed, out_pred, out_bin, n);
    } else {
        int blocks = (int)(((long)n + 255) / 256);
        if (blocks > 4096) blocks = 4096;
        hbc_direct<<<blocks, 256, 0, stream>>>(
            seg_val, seg_len, logit, bin_pos, bin_num, pos_w, out_pred, out_bin, n);
    }
}

// Round 12
// 352.262 us; speedup vs baseline: 1.0165x; 1.0165x over previous
//
#include <hip/hip_runtime.h>
#include <math.h>

// HistogramBinningCalibrationByFeature
// d_out: [0..N) calibrated_prediction (f32) | [N..2N) bin ids (f32-encoded)
//
// R11/R12 (resubmit after infra timeout): FIFO-correct two-stage pipeline.
// R10 failed because the seg_val gathers (vmem) were issued AFTER the
// next-tile prefetch: waiting for the newest loads (gathers) drains the
// whole FIFO including the prefetch. New issue order per iteration:
//   wait G_t (prefetch streams_{t+1} stay outstanding)
//   compute_t / LDS / store_t
//   wait streams_{t+1} (only stores newer)
//   issue gathers_{t+1}           <- BEFORE next prefetch
//   issue streams_{t+2}
// so every s_waitcnt leaves the newest prefetch batch in flight.
// 3-bit LDS ratio table (80.6 KB) unchanged from R8.

constexpr int kNumBins     = 5000;
constexpr int kNumSegments = 42;
constexpr int kNumInterval = (kNumSegments + 1) * kNumBins;   // 215000
constexpr int kGroups      = (kNumInterval + 31) / 32;        // 6719
constexpr int kTabWords    = kGroups * 3;                     // 20157
constexpr int kGuardWord   = kTabWords;                       // read guard
constexpr int kLpwWord     = kTabWords + 1;
constexpr int kStageWords  = kTabWords + 1;                   // table + guard
constexpr float kDecode    = 0.9995f / 6.0f;
constexpr float kEncode    = 6.0f / 0.9995f;

typedef float f32x4 __attribute__((ext_vector_type(4)));
typedef int   i32x4 __attribute__((ext_vector_type(4)));

__device__ __forceinline__ unsigned int funnel_r(unsigned int hi, unsigned int lo, int sh) {
#if __has_builtin(__builtin_amdgcn_alignbit)
    return __builtin_amdgcn_alignbit(hi, lo, (unsigned int)sh);
#else
    unsigned long long v = ((unsigned long long)hi << 32) | lo;
    return (unsigned int)(v >> sh);
#endif
}

__global__ __launch_bounds__(256) void pack_kernel(
    const float* __restrict__ bin_pos,
    const float* __restrict__ bin_num,
    const float* __restrict__ pos_w,
    unsigned int* __restrict__ packed)   // [kTabWords + 2] in d_ws
{
    const int g = blockIdx.x * 256 + threadIdx.x;
    if (g < kGroups) {
        unsigned int w[3] = {0, 0, 0};
        int bitpos = 0;
        #pragma unroll
        for (int j = 0; j < 32; ++j) {
            const int i = g * 32 + j;
            unsigned int code = 7u;                  // invalid sentinel / pad
            if (i < kNumInterval) {
                const float nm = bin_num[i];
                if (nm > 0.0f) {
                    const float r = (bin_pos[i] / nm) * 0.9995f;  // [0, 0.9995]
                    int c = (int)(r * kEncode + 0.5f);
                    c = c < 0 ? 0 : (c > 6 ? 6 : c);
                    code = (unsigned int)c;
                }
            }
            const int word = bitpos >> 5;
            const int sh   = bitpos & 31;
            w[word] |= code << sh;
            if (sh > 29 && word < 2)
                w[word + 1] |= code >> (32 - sh);
            bitpos += 3;
        }
        packed[g * 3 + 0] = w[0];
        packed[g * 3 + 1] = w[1];
        packed[g * 3 + 2] = w[2];
    }
    if (g == 0) {
        packed[kGuardWord] = 0u;
        packed[kLpwWord]   = __float_as_uint((float)log((double)pos_w[0]));
    }
}

// Unconditional clamped gathers (validity applied later via select).
__device__ __forceinline__ void issue_gathers(
    const int* __restrict__ seg_val, const i32x4& S0, const i32x4& S1,
    int nmax, int* __restrict__ G)
{
    #pragma unroll
    for (int j = 0; j < 4; ++j) {
        int a = S0[j];
        a = a < 0 ? 0 : (a > nmax - 1 ? nmax - 1 : a);
        G[j] = seg_val[a];
    }
    #pragma unroll
    for (int j = 0; j < 4; ++j) {
        int a = S1[j];
        a = a < 0 ? 0 : (a > nmax - 1 ? nmax - 1 : a);
        G[4 + j] = seg_val[a];
    }
}

__device__ __forceinline__ void process8(
    const f32x4& L0, const f32x4& L1,
    const i32x4& S0, const i32x4& S1, int sE0, int sE1,
    const int* __restrict__ G, const unsigned int* __restrict__ tab, float lpw,
    f32x4& op0, f32x4& op1, f32x4& ob0, f32x4& ob1)
{
    constexpr float kInvStep = 1.0f / 0.0002f;

    const int   s0[5] = {S0[0], S0[1], S0[2], S0[3], sE0};
    const int   s1[5] = {S1[0], S1[1], S1[2], S1[3], sE1};
    const float l[8]  = {L0[0], L0[1], L0[2], L0[3], L1[0], L1[1], L1[2], L1[3]};

    // sigmoid + raw bin (independent of gathers)
    float p[8]; int q[8];
    #pragma unroll
    for (int j = 0; j < 8; ++j) {
        const float x  = l[j] + lpw;
        const float e  = __expf(-x);
        const float pf = __builtin_amdgcn_rcpf(1.0f + e);
        p[j] = pf;
        q[j] = (int)(__builtin_ceilf(pf * kInvStep) - 1.0f);
    }

    // fold in segment offset (first use of G -> waits gathers, prefetch stays)
    int bin[8];
    #pragma unroll
    for (int j = 0; j < 4; ++j) {
        const bool v0 = s0[j + 1] > s0[j];
        const int sv0 = G[j] + 1;
        const int d0  = v0 ? ((sv0 > kNumSegments) ? 0 : sv0) : 0;
        bin[j] = q[j] + d0 * kNumBins;

        const bool v1 = s1[j + 1] > s1[j];
        const int sv1 = G[4 + j] + 1;
        const int d1  = v1 ? ((sv1 > kNumSegments) ? 0 : sv1) : 0;
        bin[4 + j] = q[4 + j] + d1 * kNumBins;
    }

    // LDS table lookups
    unsigned int lo[8], hi[8]; int sh[8];
    #pragma unroll
    for (int j = 0; j < 8; ++j) {
        int idx = bin[j];
        idx = idx < 0 ? 0 : idx;
        idx = idx > (kNumInterval - 1) ? (kNumInterval - 1) : idx;
        const int bitoff = idx * 3;
        sh[j] = bitoff & 31;
        const int w = bitoff >> 5;
        lo[j] = tab[w];
        hi[j] = tab[w + 1];
    }

    float* opp0 = (float*)&op0; float* opp1 = (float*)&op1;
    float* obp0 = (float*)&ob0; float* obp1 = (float*)&ob1;
    #pragma unroll
    for (int j = 0; j < 4; ++j) {
        const unsigned int c0 = funnel_r(hi[j], lo[j], sh[j]) & 7u;
        const unsigned int c1 = funnel_r(hi[4 + j], lo[4 + j], sh[4 + j]) & 7u;
        opp0[j] = (c0 == 7u) ? p[j]     : fmaf(p[j],     0.0005f, (float)c0 * kDecode);
        opp1[j] = (c1 == 7u) ? p[4 + j] : fmaf(p[4 + j], 0.0005f, (float)c1 * kDecode);
        obp0[j] = (float)bin[j];
        obp1[j] = (float)bin[4 + j];
    }
}

__global__ __launch_bounds__(1024, 4) void hbc_pipe2(
    const int*          __restrict__ seg_val,   // [N]
    const int*          __restrict__ seg_len,   // [N+1]
    const float*        __restrict__ logit,     // [N]
    const unsigned int* __restrict__ packed,    // [kTabWords+2] (ws)
    float*              __restrict__ out_pred,  // [N]
    float*              __restrict__ out_bin,   // [N]
    int n)
{
    __shared__ unsigned int tab[20160];          // 80640 B

    const int tid = threadIdx.x;

    for (int w = tid; w < kStageWords; w += 1024)
        tab[w] = packed[w];
    const float lpw = __uint_as_float(packed[kLpwWord]);
    __syncthreads();

    const long ntiles = (long)n >> 13;           // full 8192-elem tiles
    const long stride = gridDim.x;
    long t = blockIdx.x;

    if (t < ntiles) {
        // ---- prologue ----
        long e0 = (t << 13) + (long)tid * 4;
        long e1 = e0 + 4096;
        f32x4 L0 = __builtin_nontemporal_load((const f32x4*)(logit   + e0));
        f32x4 L1 = __builtin_nontemporal_load((const f32x4*)(logit   + e1));
        i32x4 S0 = __builtin_nontemporal_load((const i32x4*)(seg_len + e0));
        i32x4 S1 = __builtin_nontemporal_load((const i32x4*)(seg_len + e1));
        int  sE0 = seg_len[e0 + 4];
        int  sE1 = seg_len[e1 + 4];

        int G[8];
        issue_gathers(seg_val, S0, S1, n, G);    // waits streams_t (prologue only)

        long nt_ = t + stride;
        f32x4 nL0, nL1; i32x4 nS0, nS1; int nsE0 = 0, nsE1 = 0;
        bool more = nt_ < ntiles;
        if (more) {
            const long f0 = (nt_ << 13) + (long)tid * 4;
            const long f1 = f0 + 4096;
            nL0 = __builtin_nontemporal_load((const f32x4*)(logit   + f0));
            nL1 = __builtin_nontemporal_load((const f32x4*)(logit   + f1));
            nS0 = __builtin_nontemporal_load((const i32x4*)(seg_len + f0));
            nS1 = __builtin_nontemporal_load((const i32x4*)(seg_len + f1));
            nsE0 = seg_len[f0 + 4];
            nsE1 = seg_len[f1 + 4];
        }

        for (;;) {
            // ---- process tile t (G wait leaves prefetch outstanding) ----
            f32x4 op0, op1, ob0, ob1;
            process8(L0, L1, S0, S1, sE0, sE1, G, tab, lpw, op0, op1, ob0, ob1);
            __builtin_nontemporal_store(op0, (f32x4*)(out_pred + e0));
            __builtin_nontemporal_store(op1, (f32x4*)(out_pred + e1));
            __builtin_nontemporal_store(ob0, (f32x4*)(out_bin  + e0));
            __builtin_nontemporal_store(ob1, (f32x4*)(out_bin  + e1));

            if (!more) break;

            // ---- rotate: current <- prefetched ----
            t = nt_;
            e0 = (t << 13) + (long)tid * 4;
            e1 = e0 + 4096;
            L0 = nL0; L1 = nL1; S0 = nS0; S1 = nS1; sE0 = nsE0; sE1 = nsE1;

            // gathers for new t FIRST (waits streams_t; only stores newer)...
            issue_gathers(seg_val, S0, S1, n, G);

            // ...then prefetch streams for t+stride (stay outstanding)
            nt_ = t + stride;
            more = nt_ < ntiles;
            if (more) {
                const long f0 = (nt_ << 13) + (long)tid * 4;
                const long f1 = f0 + 4096;
                nL0 = __builtin_nontemporal_load((const f32x4*)(logit   + f0));
                nL1 = __builtin_nontemporal_load((const f32x4*)(logit   + f1));
                nS0 = __builtin_nontemporal_load((const i32x4*)(seg_len + f0));
                nS1 = __builtin_nontemporal_load((const i32x4*)(seg_len + f1));
                nsE0 = seg_len[f0 + 4];
                nsE1 = seg_len[f1 + 4];
            }
        }
    }

    // tail (N % 8192), scalar + bounds-checked
    constexpr float kInvStep = 1.0f / 0.0002f;
    const long tailStart = ntiles << 13;
    for (long i = tailStart + (long)blockIdx.x * 1024 + tid; i < (long)n;
         i += (long)gridDim.x * 1024) {
        const float x  = logit[i] + lpw;
        const float pf = __builtin_amdgcn_rcpf(1.0f + __expf(-x));
        int d = 0;
        if (seg_len[i + 1] > seg_len[i]) {
            const int sv = seg_val[seg_len[i]] + 1;
            d = (sv > kNumSegments) ? 0 : sv;
        }
        const int bin = (int)(__builtin_ceilf(pf * kInvStep) - 1.0f) + d * kNumBins;
        int idx = bin < 0 ? 0 : (bin > kNumInterval - 1 ? kNumInterval - 1 : bin);
        const int bitoff = idx * 3;
        const unsigned int code =
            funnel_r(tab[(bitoff >> 5) + 1], tab[bitoff >> 5], bitoff & 31) & 7u;
        const float r = (float)code * kDecode;
        out_pred[i] = (code == 7u) ? pf : fmaf(pf, 0.0005f, r);
        out_bin[i]  = (float)bin;
    }
}

// Fallback if ws is too small: direct two-table global-gather version.
__global__ __launch_bounds__(256) void hbc_direct(
    const int*   __restrict__ seg_val,
    const int*   __restrict__ seg_len,
    const float* __restrict__ logit,
    const float* __restrict__ bin_pos,
    const float* __restrict__ bin_num,
    const float* __restrict__ pos_w,
    float*       __restrict__ out_pred,
    float*       __restrict__ out_bin,
    int n)
{
    const float kStep = 0.0002f;
    const float lpw = logf(pos_w[0]);
    for (long i = (long)blockIdx.x * blockDim.x + threadIdx.x; i < (long)n;
         i += (long)gridDim.x * blockDim.x) {
        const float x  = logit[i] + lpw;
        const float pf = 1.0f / (1.0f + expf(-x));
        int d = 0;
        if (seg_len[i + 1] > seg_len[i]) {
            const int sv = seg_val[seg_len[i]] + 1;
            d = (sv > kNumSegments) ? 0 : sv;
        }
        const int bin = (int)(ceilf(pf / kStep) - 1.0f) + d * kNumBins;
        int idx = bin < 0 ? 0 : (bin > kNumInterval - 1 ? kNumInterval - 1 : bin);
        const float cp = bin_pos[idx];
        const float cn = bin_num[idx];
        const float ctr = (cp / cn) * 0.9995f + pf * 0.0005f;
        out_pred[i] = (cn > 0.0f) ? ctr : pf;
        out_bin[i]  = (float)bin;
    }
}

extern "C" void kernel_launch(void* const* d_in, const int* in_sizes, int n_in,
                              void* d_out, int out_size, void* d_ws, size_t ws_size,
                              hipStream_t stream) {
    const int*   seg_val = (const int*)  d_in[0];
    const int*   seg_len = (const int*)  d_in[1];
    const float* logit   = (const float*)d_in[2];
    const float* bin_pos = (const float*)d_in[3];
    const float* bin_num = (const float*)d_in[4];
    const float* pos_w   = (const float*)d_in[5];

    const int n = in_sizes[2];
    float* out_pred = (float*)d_out;
    float* out_bin  = (float*)d_out + n;

    const size_t ws_needed = (size_t)(kTabWords + 2) * sizeof(unsigned int);

    if (ws_size >= ws_needed) {
        unsigned int* packed = (unsigned int*)d_ws;
        const int blocks_prep = (kGroups + 255) / 256;
        pack_kernel<<<blocks_prep, 256, 0, stream>>>(bin_pos, bin_num, pos_w, packed);
        hbc_pipe2<<<512, 1024, 0, stream>>>(
            seg_val, seg_len, logit, packed, out_pred, out_bin, n);
    } else {
        int blocks = (int)(((long)n + 255) / 256);
        if (blocks > 4096) blocks = 4096;
        hbc_direct<<<blocks, 256, 0, stream>>>(
            seg_val, seg_len, logit, bin_pos, bin_num, pos_w, out_pred, out_bin, n);
    }
}